// Round 8
// baseline (161.772 us; speedup 1.0000x reference)
//
#include <hip/hip_runtime.h>
#include <hip/hip_bf16.h>
#include <cmath>

// Problem dims (fixed by reference): B=2, T=2048, C=1024, H=16, D=64
// Inputs fp32, output fp32.
#define TB   2048
#define CCH  1024
#define NCH  32      // chunks per (b,h): T / 64
#define EPSF 1e-6f

typedef unsigned short u16;
typedef __attribute__((ext_vector_type(8))) short  frag8;   // 8 bf16 (4 VGPRs)
typedef __attribute__((ext_vector_type(4))) float  floatx4; // MFMA C/D

// RNE float -> bf16 (finite inputs only)
__device__ __forceinline__ u16 f2bf(float f) {
    unsigned int u = __float_as_uint(f);
    unsigned int r = (u + 0x7fffu + ((u >> 16) & 1u)) >> 16;
    return (u16)r;
}
__device__ __forceinline__ float bf2f(u16 v) {
    return __uint_as_float(((unsigned int)v) << 16);
}

// Async global->LDS, 16 B per lane (wave-uniform base + lane*16; unpadded dest).
__device__ __forceinline__ void async_load16(const u16* g, u16* l) {
    __builtin_amdgcn_global_load_lds(
        (const __attribute__((address_space(1))) void*)g,
        (__attribute__((address_space(3))) void*)l,
        16, 0, 0);
}

// ---------------------------------------------------------------------------
// Fused prep: [0,2048) cvt x->bf16 ; [2048,2816) transpose w_attn ; rest w_proj.
// ---------------------------------------------------------------------------
__global__ __launch_bounds__(256) void prep_k(
    const float* __restrict__ x, const float* __restrict__ wa,
    const float* __restrict__ wp,
    u16* __restrict__ xb, u16* __restrict__ waT, u16* __restrict__ wpT)
{
    __shared__ u16 t[64][72];   // t[n][k]
    int blk = blockIdx.x;
    if (blk < 2048) {                       // cvt: 4096*1024 elems, 8/thread
        int i = (blk * 256 + threadIdx.x) * 8;
        float4 a = *(const float4*)(x + i);
        float4 b = *(const float4*)(x + i + 4);
        u16 v[8];
        v[0] = f2bf(a.x); v[1] = f2bf(a.y); v[2] = f2bf(a.z); v[3] = f2bf(a.w);
        v[4] = f2bf(b.x); v[5] = f2bf(b.y); v[6] = f2bf(b.z); v[7] = f2bf(b.w);
        *(uint4*)(xb + i) = *(uint4*)v;
        return;
    }
    const float* in; u16* out; int K, N, bx, by;
    if (blk < 2048 + 768) {                 // w_attn^T: (1024 x 3072) -> (3072 x 1024)
        int tb = blk - 2048; in = wa; out = waT; K = 1024; N = 3072;
        bx = tb % 48; by = tb / 48;
    } else {                                // w_proj^T: (1024 x 1024)
        int tb = blk - 2816; in = wp; out = wpT; K = 1024; N = 1024;
        bx = tb & 15; by = tb >> 4;
    }
    const int k0 = by * 64, n0 = bx * 64;
    #pragma unroll
    for (int i = 0; i < 4; ++i) {
        int rr = (threadIdx.x >> 4) + 16 * i;          // k-row
        int c4 = (threadIdx.x & 15) * 4;               // n-col
        float4 v = *(const float4*)(in + (size_t)(k0 + rr) * N + n0 + c4);
        t[c4 + 0][rr] = f2bf(v.x);
        t[c4 + 1][rr] = f2bf(v.y);
        t[c4 + 2][rr] = f2bf(v.z);
        t[c4 + 3][rr] = f2bf(v.w);
    }
    __syncthreads();
    #pragma unroll
    for (int i = 0; i < 2; ++i) {
        int rr = (threadIdx.x >> 3) + 32 * i;          // n-row
        int c8 = (threadIdx.x & 7) * 8;                // k-chunk
        u16 o[8];
        #pragma unroll
        for (int q = 0; q < 8; ++q) o[q] = t[rr][c8 + q];
        *(uint4*)(out + (size_t)(n0 + rr) * K + k0 + c8) = *(uint4*)o;
    }
}

// ---------------------------------------------------------------------------
// GEMM1: qkv(bf16) = phi(x @ w_attn), phi on cols < phi_cols.
// 256x192 tile, BK=64, 512 threads (8 waves, 4M x 2N), dbuf LDS (112 KB),
// counted vmcnt(7), grid 16x16 = 256 blocks = 1/CU full coverage, zero tail.
// Staged volume 235 MB (vs 335 at 128x192). Inner loop / fragment math /
// epilogue byte-identical to the verified R4 gemm1 (wm*64, wn*96, acc[4][6]).
// Bijective XCD swizzle: each XCD owns 2 contiguous tile-rows.
// ---------------------------------------------------------------------------
__global__ __launch_bounds__(512, 1) void gemm1_k(
    const u16* __restrict__ A, const u16* __restrict__ BT,
    u16* __restrict__ C, int N, int K, int phi_cols)
{
    __shared__ u16 Als[2][256 * 64];   // 32 KB x2
    __shared__ u16 Bls[2][192 * 64];   // 24 KB x2
    const int tid  = threadIdx.x;
    const int wave = tid >> 6, lane = tid & 63;
    const int quad = lane >> 4, lrow = lane & 15;
    const int wm = wave >> 1, wn = wave & 1;   // 4M x 2N wave grid
    const int lr = lane >> 3;
    const int lc = ((lane & 7) ^ lr) * 8;
    const int rsw = lrow & 7;
    floatx4 acc[4][6] = {};
    const int NT = K >> 6;                 // 16 K-tiles

    // XCD swizzle: 256 blocks, 256%8==0 -> bijective; XCD gets 2 tile-rows
    const int bid = blockIdx.x;
    const int swz = (bid & 7) * 32 + (bid >> 3);
    const int row0 = (swz >> 4) * 256, col0 = (swz & 15) * 192;

    // prologue: stage tile 0 (A: 4 groups/wave of 32, B: 3 of 24)
    #pragma unroll
    for (int m = 0; m < 4; ++m) {
        int i = wave * 4 + m;
        async_load16(A + (size_t)(row0 + i * 8 + lr) * K + lc, &Als[0][i * 512]);
    }
    #pragma unroll
    for (int m = 0; m < 3; ++m) {
        int i = wave * 3 + m;
        async_load16(BT + (size_t)(col0 + i * 8 + lr) * K + lc, &Bls[0][i * 512]);
    }

    for (int t = 0; t < NT; ++t) {
        const int p = t & 1;
        if (t + 1 < NT) {
            const int k0 = (t + 1) << 6;
            #pragma unroll
            for (int m = 0; m < 4; ++m) {
                int i = wave * 4 + m;
                async_load16(A + (size_t)(row0 + i * 8 + lr) * K + k0 + lc,
                             &Als[p ^ 1][i * 512]);
            }
            #pragma unroll
            for (int m = 0; m < 3; ++m) {
                int i = wave * 3 + m;
                async_load16(BT + (size_t)(col0 + i * 8 + lr) * K + k0 + lc,
                             &Bls[p ^ 1][i * 512]);
            }
            __builtin_amdgcn_sched_barrier(0);
            asm volatile("s_waitcnt vmcnt(7)" ::: "memory");   // tile t landed
        } else {
            asm volatile("s_waitcnt vmcnt(0)" ::: "memory");
        }
        __builtin_amdgcn_s_barrier();
        __builtin_amdgcn_sched_barrier(0);

        #pragma unroll
        for (int ksi = 0; ksi < 2; ++ksi) {
            frag8 af[4], bf[6];
            #pragma unroll
            for (int i = 0; i < 4; ++i)
                af[i] = *(const frag8*)&Als[p][(wm * 64 + i * 16 + lrow) * 64
                                              + ((ksi * 4 + quad) ^ rsw) * 8];
            #pragma unroll
            for (int j = 0; j < 6; ++j)
                bf[j] = *(const frag8*)&Bls[p][(wn * 96 + j * 16 + lrow) * 64
                                              + ((ksi * 4 + quad) ^ rsw) * 8];
            #pragma unroll
            for (int i = 0; i < 4; ++i)
                #pragma unroll
                for (int j = 0; j < 6; ++j)
                    acc[i][j] = __builtin_amdgcn_mfma_f32_16x16x32_bf16(
                        af[i], bf[j], acc[i][j], 0, 0, 0);
        }

        asm volatile("s_waitcnt lgkmcnt(0)" ::: "memory");
        __builtin_amdgcn_sched_barrier(0);
        __builtin_amdgcn_s_barrier();
    }

    #pragma unroll
    for (int i = 0; i < 4; ++i) {
        #pragma unroll
        for (int j = 0; j < 6; ++j) {
            int col = col0 + wn * 96 + j * 16 + lrow;
            bool isphi = col < phi_cols;
            #pragma unroll
            for (int r = 0; r < 4; ++r) {
                int row = row0 + wm * 64 + i * 16 + quad * 4 + r;
                float v = acc[i][j][r];
                if (isphi) v = (v > 0.f) ? (v + 1.f) : __expf(v);  // phi = elu+1
                C[(size_t)row * N + col] = f2bf(v);
            }
        }
    }
}

// ---------------------------------------------------------------------------
// GEMM2: out(fp32) = Y @ w_proj. 128x128 tile, 512 threads (8 waves, 2Mx4N),
// BK=64 dbuf, counted vmcnt(4). Grid 8x32 = 256 blocks, 1 block/CU x 8 waves.
// ---------------------------------------------------------------------------
__global__ __launch_bounds__(512, 1) void gemm_bf16_f32out_k(
    const u16* __restrict__ A, const u16* __restrict__ BT,
    float* __restrict__ C, int N, int K)
{
    __shared__ u16 Als[2][128 * 64];   // 16 KB x2
    __shared__ u16 Bls[2][128 * 64];   // 16 KB x2
    const int tid  = threadIdx.x;
    const int wave = tid >> 6, lane = tid & 63;
    const int quad = lane >> 4, lrow = lane & 15;
    const int wm = wave >> 2, wn = wave & 3;   // 2M x 4N wave grid
    const int row0 = blockIdx.y * 128, col0 = blockIdx.x * 128;
    const int lr = lane >> 3;
    const int lc = ((lane & 7) ^ lr) * 8;
    const int rsw = lrow & 7;
    floatx4 acc[4][2] = {};
    const int NT = K >> 6;

    #pragma unroll
    for (int m = 0; m < 2; ++m) {
        int i = wave * 2 + m;                  // 16 groups of 8 rows
        async_load16(A + (size_t)(row0 + i * 8 + lr) * K + lc, &Als[0][i * 512]);
        async_load16(BT + (size_t)(col0 + i * 8 + lr) * K + lc, &Bls[0][i * 512]);
    }

    for (int t = 0; t < NT; ++t) {
        const int p = t & 1;
        if (t + 1 < NT) {
            const int k0 = (t + 1) << 6;
            #pragma unroll
            for (int m = 0; m < 2; ++m) {
                int i = wave * 2 + m;
                async_load16(A + (size_t)(row0 + i * 8 + lr) * K + k0 + lc,
                             &Als[p ^ 1][i * 512]);
                async_load16(BT + (size_t)(col0 + i * 8 + lr) * K + k0 + lc,
                             &Bls[p ^ 1][i * 512]);
            }
            __builtin_amdgcn_sched_barrier(0);
            asm volatile("s_waitcnt vmcnt(4)" ::: "memory");
        } else {
            asm volatile("s_waitcnt vmcnt(0)" ::: "memory");
        }
        __builtin_amdgcn_s_barrier();
        __builtin_amdgcn_sched_barrier(0);

        #pragma unroll
        for (int ksi = 0; ksi < 2; ++ksi) {
            frag8 af[4], bf[2];
            #pragma unroll
            for (int i = 0; i < 4; ++i)
                af[i] = *(const frag8*)&Als[p][(wm * 64 + i * 16 + lrow) * 64
                                              + ((ksi * 4 + quad) ^ rsw) * 8];
            #pragma unroll
            for (int jn = 0; jn < 2; ++jn)
                bf[jn] = *(const frag8*)&Bls[p][(wn * 32 + jn * 16 + lrow) * 64
                                               + ((ksi * 4 + quad) ^ rsw) * 8];
            #pragma unroll
            for (int i = 0; i < 4; ++i)
                #pragma unroll
                for (int jn = 0; jn < 2; ++jn)
                    acc[i][jn] = __builtin_amdgcn_mfma_f32_16x16x32_bf16(
                        af[i], bf[jn], acc[i][jn], 0, 0, 0);
        }

        asm volatile("s_waitcnt lgkmcnt(0)" ::: "memory");
        __builtin_amdgcn_sched_barrier(0);
        __builtin_amdgcn_s_barrier();
    }

    #pragma unroll
    for (int i = 0; i < 4; ++i)
        #pragma unroll
        for (int jn = 0; jn < 2; ++jn) {
            int col = col0 + wn * 32 + jn * 16 + lrow;
            #pragma unroll
            for (int r = 0; r < 4; ++r) {
                int row = row0 + wm * 64 + i * 16 + quad * 4 + r;
                C[(size_t)row * N + col] = acc[i][jn][r];
            }
        }
}

// ---------------------------------------------------------------------------
// chunk_kv (MFMA): S_c^T = V^T K (bf16 [j][i]); z_c = colsum K; V^T exported
// to VtG (plain stores, no fences) for attn's async staging.
// Grid 1024 blocks ((b*16+h)*32+c), 256 threads = 4 waves.
// ---------------------------------------------------------------------------
__global__ __launch_bounds__(256) void chunk_kv_mfma_k(
    const u16* __restrict__ qkv,
    u16* __restrict__ Spt,
    float* __restrict__ zloc,
    u16* __restrict__ VtG)
{
    __shared__ u16 Kt[64][72];   // K^T [d][s]
    __shared__ u16 Vt[64][72];   // V^T [j][s]
    const int tid  = threadIdx.x;
    const int wave = tid >> 6, lane = tid & 63;
    const int quad = lane >> 4, lrow = lane & 15;
    const int blk = blockIdx.x;
    const int c = blk & 31, h = (blk >> 5) & 15, b = blk >> 9;
    const int t0 = c * 64;
    const u16* base = qkv + (size_t)(b * TB + t0) * 3072 + h * 64;

    #pragma unroll
    for (int m = 0; m < 2; ++m) {
        int chunk = tid + 256 * m;
        int s = chunk >> 3, d0 = (chunk & 7) * 8;
        const u16* row = base + (size_t)s * 3072;
        u16 kv[8], vv[8];
        *(uint4*)kv = *(const uint4*)(row + 1024 + d0);
        *(uint4*)vv = *(const uint4*)(row + 2048 + d0);
        #pragma unroll
        for (int q = 0; q < 8; ++q) { Kt[d0 + q][s] = kv[q]; Vt[d0 + q][s] = vv[q]; }
    }
    __syncthreads();

    // export V^T (row-major [j][s]) for attn's async staging
    #pragma unroll
    for (int m = 0; m < 2; ++m) {
        int e = tid + 256 * m;
        int r = e >> 3, c8 = (e & 7) * 8;
        u16 o[8];
        #pragma unroll
        for (int q = 0; q < 8; ++q) o[q] = Vt[r][c8 + q];
        *(uint4*)(VtG + (size_t)blk * 4096 + r * 64 + c8) = *(uint4*)o;
    }

    frag8 vf[2];
    #pragma unroll
    for (int ks = 0; ks < 2; ++ks)
        vf[ks] = *(const frag8*)&Vt[wave * 16 + lrow][ks * 32 + quad * 8];
    u16* So = Spt + (size_t)blk * 4096;
    #pragma unroll
    for (int jn = 0; jn < 4; ++jn) {
        floatx4 acc = {};
        #pragma unroll
        for (int ks = 0; ks < 2; ++ks) {
            frag8 kf = *(const frag8*)&Kt[jn * 16 + lrow][ks * 32 + quad * 8];
            acc = __builtin_amdgcn_mfma_f32_16x16x32_bf16(vf[ks], kf, acc, 0, 0, 0);
        }
        #pragma unroll
        for (int r = 0; r < 4; ++r) {
            int j = wave * 16 + quad * 4 + r;     // row of S^T
            int i = jn * 16 + lrow;               // col of S^T
            So[j * 64 + i] = f2bf(acc[r]);
        }
    }
    if (tid < 64) {
        float z = 0.f;
        for (int s = 0; s < 64; ++s) z += bf2f(Kt[tid][s]);
        zloc[(size_t)blk * 64 + tid] = z;
    }
}

// ---------------------------------------------------------------------------
// Exclusive prefix over chunk axis, IN-PLACE on bf16 Spt, VECTORIZED:
// each thread owns 4 consecutive bf16 (uint2). Grid: 32 bh x 4 parts = 128.
// ---------------------------------------------------------------------------
__global__ __launch_bounds__(256) void scan_state_k(
    u16* __restrict__ Spt, float* __restrict__ z)
{
    const int bh = blockIdx.x >> 2;
    const int part = blockIdx.x & 3;
    const int e0 = part * 1024 + threadIdx.x * 4;
    const size_t base = (size_t)bh * NCH * 4096;
    float r[4] = {};
    for (int c = 0; c < NCH; ++c) {
        u16* p = Spt + base + (size_t)c * 4096 + e0;
        u16 t[4];
        *(uint2*)t = *(const uint2*)p;
        u16 o[4];
        #pragma unroll
        for (int q = 0; q < 4; ++q) { o[q] = f2bf(r[q]); r[q] += bf2f(t[q]); }
        *(uint2*)p = *(uint2*)o;
    }
    if (part == 0 && threadIdx.x < 64) {
        const size_t zb = (size_t)bh * NCH * 64;
        float rz = 0.f;
        for (int c = 0; c < NCH; ++c) {
            float t = z[zb + c * 64 + threadIdx.x];
            z[zb + c * 64 + threadIdx.x] = rz;
            rz += t;
        }
    }
}

// ---------------------------------------------------------------------------
// attn (MFMA): y = (Q*Sp^T + causal(QK^T)*V) / (q.zp + rowsum + eps), bf16 out.
// All four operand tiles staged ASYNC into unpadded XOR-swizzled LDS
// (Q,K from qkv; Sp from scanned Spt; V^T from VtG). 1024 blocks, 4 waves.
// ---------------------------------------------------------------------------
__global__ __launch_bounds__(256) void attn_mfma_k(
    const u16* __restrict__ qkv,
    const u16* __restrict__ SptG,
    const float* __restrict__ zp,
    const u16* __restrict__ VtG,
    u16* __restrict__ Yb)
{
    __shared__ u16 Qls[64 * 64];   // Q [t][d] swizzled; reused as Y staging (plain)
    __shared__ u16 Kls[64 * 64];   // K [s][d] swizzled
    __shared__ u16 Vls[64 * 64];   // V^T [j][s] swizzled
    __shared__ u16 Sls[64 * 64];   // Sp^T [j][d] swizzled; then masked A [t][s]
    __shared__ float zps[64];
    __shared__ float den4[64][4];
    __shared__ float den[64];

    const int tid  = threadIdx.x;
    const int wave = tid >> 6, lane = tid & 63;
    const int quad = lane >> 4, lrow = lane & 15;
    const int blk = blockIdx.x;
    const int c = blk & 31, h = (blk >> 5) & 15, b = blk >> 9;
    const int t0 = c * 64;
    const int lr = lane >> 3;
    const int lc = ((lane & 7) ^ lr) * 8;
    const int rsw = lrow & 7;
    const u16* qbase = qkv + (size_t)(b * TB + t0) * 3072 + h * 64;

    #pragma unroll
    for (int m = 0; m < 2; ++m) {
        int i = wave * 2 + m;          // 8-row group 0..7
        int r = i * 8 + lr;
        async_load16(qbase + (size_t)r * 3072 + lc,          &Qls[i * 512]);
        async_load16(qbase + (size_t)r * 3072 + 1024 + lc,   &Kls[i * 512]);
        async_load16(SptG + (size_t)blk * 4096 + r * 64 + lc, &Sls[i * 512]);
        async_load16(VtG  + (size_t)blk * 4096 + r * 64 + lc, &Vls[i * 512]);
    }
    if (tid < 64) zps[tid] = zp[(size_t)blk * 64 + tid];
    __syncthreads();

    frag8 qf[2];
    #pragma unroll
    for (int ks = 0; ks < 2; ++ks)
        qf[ks] = *(const frag8*)&Qls[(wave * 16 + lrow) * 64 + ((ks * 4 + quad) ^ rsw) * 8];

    floatx4 yacc[4] = {}, kacc[4] = {};
    #pragma unroll
    for (int jn = 0; jn < 4; ++jn) {
        #pragma unroll
        for (int ks = 0; ks < 2; ++ks) {
            frag8 spf = *(const frag8*)&Sls[(jn * 16 + lrow) * 64 + ((ks * 4 + quad) ^ rsw) * 8];
            yacc[jn] = __builtin_amdgcn_mfma_f32_16x16x32_bf16(qf[ks], spf, yacc[jn], 0, 0, 0);
            frag8 kf = *(const frag8*)&Kls[(jn * 16 + lrow) * 64 + ((ks * 4 + quad) ^ rsw) * 8];
            kacc[jn] = __builtin_amdgcn_mfma_f32_16x16x32_bf16(qf[ks], kf, kacc[jn], 0, 0, 0);
        }
    }
    __syncthreads();   // done reading Sls; reuse for masked A (swizzled [t][s])

    #pragma unroll
    for (int jn = 0; jn < 4; ++jn) {
        int s = jn * 16 + lrow;
        #pragma unroll
        for (int r = 0; r < 4; ++r) {
            int t = wave * 16 + quad * 4 + r;
            float v = (s <= t) ? kacc[jn][r] : 0.f;
            Sls[t * 64 + (((s >> 3) ^ (t & 7)) * 8) + (s & 7)] = f2bf(v);
        }
    }
    __syncthreads();

    // den partials: den[t] = sum_d Q[t][d]*zp[d] + sum_s A[t][s]  (swizzle-aware)
    {
        int t = tid >> 2, seg = tid & 3;
        float p = 0.f;
        #pragma unroll
        for (int g2 = 0; g2 < 2; ++g2) {
            int g = seg * 2 + g2;
            int pq = ((g ^ (t & 7)) * 8);
            const u16* qp = &Qls[t * 64 + pq];
            const u16* ap = &Sls[t * 64 + pq];
            #pragma unroll
            for (int e = 0; e < 8; ++e) {
                p += bf2f(qp[e]) * zps[g * 8 + e] + bf2f(ap[e]);
            }
        }
        den4[t][seg] = p;
    }

    // y += A @ V
    frag8 af2[2];
    #pragma unroll
    for (int ks = 0; ks < 2; ++ks)
        af2[ks] = *(const frag8*)&Sls[(wave * 16 + lrow) * 64 + ((ks * 4 + quad) ^ rsw) * 8];
    #pragma unroll
    for (int jn = 0; jn < 4; ++jn)
        #pragma unroll
        for (int ks = 0; ks < 2; ++ks) {
            frag8 vf = *(const frag8*)&Vls[(jn * 16 + lrow) * 64 + ((ks * 4 + quad) ^ rsw) * 8];
            yacc[jn] = __builtin_amdgcn_mfma_f32_16x16x32_bf16(af2[ks], vf, yacc[jn], 0, 0, 0);
        }
    __syncthreads();
    if (tid < 64) den[tid] = den4[tid][0] + den4[tid][1] + den4[tid][2] + den4[tid][3];
    __syncthreads();

    // epilogue: normalize, stage into Qls (plain layout), vectorized store
    #pragma unroll
    for (int jn = 0; jn < 4; ++jn) {
        #pragma unroll
        for (int r = 0; r < 4; ++r) {
            int t = wave * 16 + quad * 4 + r;
            float inv = 1.f / (den[t] + EPSF);
            Qls[t * 64 + jn * 16 + lrow] = f2bf(yacc[jn][r] * inv);
        }
    }
    __syncthreads();
    {
        int row = tid >> 2, seg = tid & 3;
        size_t o = (size_t)(b * TB + t0 + row) * CCH + h * 64 + seg * 16;
        *(uint4*)(Yb + o)     = *(uint4*)&Qls[row * 64 + seg * 16];
        *(uint4*)(Yb + o + 8) = *(uint4*)&Qls[row * 64 + seg * 16 + 8];
    }
}

// ---------------------------------------------------------------------------
extern "C" void kernel_launch(void* const* d_in, const int* in_sizes, int n_in,
                              void* d_out, int out_size, void* d_ws, size_t ws_size,
                              hipStream_t stream)
{
    const float* x      = (const float*)d_in[0]; // (2,2048,1024) fp32
    const float* w_attn = (const float*)d_in[1]; // (1024,3072)   fp32
    const float* w_proj = (const float*)d_in[2]; // (1024,1024)   fp32
    float* out = (float*)d_out;                  // (2,2048,1024) fp32

    // Workspace layout:
    //   xb    : 4096*1024 bf16  (8 MB)
    //   waT   : 3072*1024 bf16  (6 MB)
    //   wpT   : 1024*1024 bf16  (2 MB)
    //   Yb    : 4096*1024 bf16  (8 MB)
    //   qkv_b : 4096*3072 bf16  (24 MB)
    //   Spt   : 1024*4096 bf16  (8 MB)
    //   VtG   : 1024*4096 bf16  (8 MB)
    //   zloc  : 1024*64   fp32  (0.25 MB)
    u16* xb    = (u16*)d_ws;
    u16* waT   = xb    + (size_t)4096 * 1024;
    u16* wpT   = waT   + (size_t)3072 * 1024;
    u16* Yb    = wpT   + (size_t)1024 * 1024;
    u16* qkv_b = Yb    + (size_t)4096 * 1024;
    u16* Spt   = qkv_b + (size_t)4096 * 3072;
    u16* VtG   = Spt   + (size_t)1024 * 4096;
    float* zloc = (float*)(VtG + (size_t)1024 * 4096);

    // Prep (fused): cvt x, transpose w_attn, transpose w_proj
    prep_k<<<3072, 256, 0, stream>>>(x, w_attn, w_proj, xb, waT, wpT);

    // GEMM1: qkv(bf16) = phi(x @ w_attn) (phi on q,k thirds: cols < 2048)
    // 256x192 tiles: grid 256 blocks (1/CU), 512 threads, XCD-swizzled
    gemm1_k<<<256, 512, 0, stream>>>(xb, waT, qkv_b, 3072, 1024, 2048);

    // Chunked causal linear attention
    chunk_kv_mfma_k<<<1024, 256, 0, stream>>>(qkv_b, Spt, zloc, VtG);
    scan_state_k   <<<128,  256, 0, stream>>>(Spt, zloc);
    attn_mfma_k    <<<1024, 256, 0, stream>>>(qkv_b, Spt, zloc, VtG, Yb);

    // GEMM2: out = Y @ w_proj (128x128 tiles, 512 thr, BK=64 dbuf -> 256 blocks)
    gemm_bf16_f32out_k<<<dim3(8, 32), 512, 0, stream>>>(Yb, wpT, out, 1024, 1024);
}

// Round 9
// 158.117 us; speedup vs baseline: 1.0231x; 1.0231x over previous
//
#include <hip/hip_runtime.h>
#include <hip/hip_bf16.h>
#include <cmath>

// Problem dims (fixed by reference): B=2, T=2048, C=1024, H=16, D=64
// Inputs fp32, output fp32.
#define TB   2048
#define CCH  1024
#define NCH  32      // chunks per (b,h): T / 64
#define EPSF 1e-6f

typedef unsigned short u16;
typedef __attribute__((ext_vector_type(8))) short  frag8;   // 8 bf16 (4 VGPRs)
typedef __attribute__((ext_vector_type(4))) float  floatx4; // MFMA C/D

// RNE float -> bf16 (finite inputs only)
__device__ __forceinline__ u16 f2bf(float f) {
    unsigned int u = __float_as_uint(f);
    unsigned int r = (u + 0x7fffu + ((u >> 16) & 1u)) >> 16;
    return (u16)r;
}
__device__ __forceinline__ float bf2f(u16 v) {
    return __uint_as_float(((unsigned int)v) << 16);
}

// Async global->LDS, 16 B per lane (wave-uniform base + lane*16; unpadded dest).
__device__ __forceinline__ void async_load16(const u16* g, u16* l) {
    __builtin_amdgcn_global_load_lds(
        (const __attribute__((address_space(1))) void*)g,
        (__attribute__((address_space(3))) void*)l,
        16, 0, 0);
}

// ---------------------------------------------------------------------------
// Fused prep: [0,2048) cvt x->bf16 ; [2048,2816) transpose w_attn ; rest w_proj.
// ---------------------------------------------------------------------------
__global__ __launch_bounds__(256) void prep_k(
    const float* __restrict__ x, const float* __restrict__ wa,
    const float* __restrict__ wp,
    u16* __restrict__ xb, u16* __restrict__ waT, u16* __restrict__ wpT)
{
    __shared__ u16 t[64][72];   // t[n][k]
    int blk = blockIdx.x;
    if (blk < 2048) {                       // cvt: 4096*1024 elems, 8/thread
        int i = (blk * 256 + threadIdx.x) * 8;
        float4 a = *(const float4*)(x + i);
        float4 b = *(const float4*)(x + i + 4);
        u16 v[8];
        v[0] = f2bf(a.x); v[1] = f2bf(a.y); v[2] = f2bf(a.z); v[3] = f2bf(a.w);
        v[4] = f2bf(b.x); v[5] = f2bf(b.y); v[6] = f2bf(b.z); v[7] = f2bf(b.w);
        *(uint4*)(xb + i) = *(uint4*)v;
        return;
    }
    const float* in; u16* out; int K, N, bx, by;
    if (blk < 2048 + 768) {                 // w_attn^T: (1024 x 3072) -> (3072 x 1024)
        int tb = blk - 2048; in = wa; out = waT; K = 1024; N = 3072;
        bx = tb % 48; by = tb / 48;
    } else {                                // w_proj^T: (1024 x 1024)
        int tb = blk - 2816; in = wp; out = wpT; K = 1024; N = 1024;
        bx = tb & 15; by = tb >> 4;
    }
    const int k0 = by * 64, n0 = bx * 64;
    #pragma unroll
    for (int i = 0; i < 4; ++i) {
        int rr = (threadIdx.x >> 4) + 16 * i;          // k-row
        int c4 = (threadIdx.x & 15) * 4;               // n-col
        float4 v = *(const float4*)(in + (size_t)(k0 + rr) * N + n0 + c4);
        t[c4 + 0][rr] = f2bf(v.x);
        t[c4 + 1][rr] = f2bf(v.y);
        t[c4 + 2][rr] = f2bf(v.z);
        t[c4 + 3][rr] = f2bf(v.w);
    }
    __syncthreads();
    #pragma unroll
    for (int i = 0; i < 2; ++i) {
        int rr = (threadIdx.x >> 3) + 32 * i;          // n-row
        int c8 = (threadIdx.x & 7) * 8;                // k-chunk
        u16 o[8];
        #pragma unroll
        for (int q = 0; q < 8; ++q) o[q] = t[rr][c8 + q];
        *(uint4*)(out + (size_t)(n0 + rr) * K + k0 + c8) = *(uint4*)o;
    }
}

// ---------------------------------------------------------------------------
// GEMM1: qkv(bf16) = phi(x @ w_attn), phi on cols < phi_cols.
// 128x192 tile, BK=64, dbuf LDS (80 KB -> 2 blocks/CU), counted vmcnt(10).
// R4-verified structure + bijective XCD swizzle with COLUMN ownership:
// 512 blocks, swz=(bid&7)*64+(bid>>3); XCD x owns tile-cols {2x,2x+1} x all
// 32 rows -> per-XCD B working set 768 KB (L2-resident), A streams from L3.
// ---------------------------------------------------------------------------
__global__ __launch_bounds__(256, 2) void gemm1_k(
    const u16* __restrict__ A, const u16* __restrict__ BT,
    u16* __restrict__ C, int N, int K, int phi_cols)
{
    __shared__ u16 Als[2][128 * 64];   // 16 KB x2
    __shared__ u16 Bls[2][192 * 64];   // 24 KB x2
    const int tid  = threadIdx.x;
    const int wave = tid >> 6, lane = tid & 63;
    const int quad = lane >> 4, lrow = lane & 15;
    const int wm = wave >> 1, wn = wave & 1;
    const int lr = lane >> 3;
    const int lc = ((lane & 7) ^ lr) * 8;
    const int rsw = lrow & 7;
    floatx4 acc[4][6] = {};
    const int NT = K >> 6;                 // 16 K-tiles

    // XCD swizzle (bijective, 512%8==0): XCD owns 2 tile-cols x 32 rows
    const int bid = blockIdx.x;
    const int swz = (bid & 7) * 64 + (bid >> 3);
    const int row0 = (swz & 31) * 128, col0 = (swz >> 5) * 192;

    #pragma unroll
    for (int m = 0; m < 4; ++m) {
        int i = wave * 4 + m;
        async_load16(A + (size_t)(row0 + i * 8 + lr) * K + lc, &Als[0][i * 512]);
    }
    #pragma unroll
    for (int m = 0; m < 6; ++m) {
        int i = wave * 6 + m;
        async_load16(BT + (size_t)(col0 + i * 8 + lr) * K + lc, &Bls[0][i * 512]);
    }

    for (int t = 0; t < NT; ++t) {
        const int p = t & 1;
        if (t + 1 < NT) {
            const int k0 = (t + 1) << 6;
            #pragma unroll
            for (int m = 0; m < 4; ++m) {
                int i = wave * 4 + m;
                async_load16(A + (size_t)(row0 + i * 8 + lr) * K + k0 + lc,
                             &Als[p ^ 1][i * 512]);
            }
            #pragma unroll
            for (int m = 0; m < 6; ++m) {
                int i = wave * 6 + m;
                async_load16(BT + (size_t)(col0 + i * 8 + lr) * K + k0 + lc,
                             &Bls[p ^ 1][i * 512]);
            }
            __builtin_amdgcn_sched_barrier(0);
            asm volatile("s_waitcnt vmcnt(10)" ::: "memory");   // tile t landed
        } else {
            asm volatile("s_waitcnt vmcnt(0)" ::: "memory");
        }
        __builtin_amdgcn_s_barrier();
        __builtin_amdgcn_sched_barrier(0);

        #pragma unroll
        for (int ksi = 0; ksi < 2; ++ksi) {
            frag8 af[4], bf[6];
            #pragma unroll
            for (int i = 0; i < 4; ++i)
                af[i] = *(const frag8*)&Als[p][(wm * 64 + i * 16 + lrow) * 64
                                              + ((ksi * 4 + quad) ^ rsw) * 8];
            #pragma unroll
            for (int j = 0; j < 6; ++j)
                bf[j] = *(const frag8*)&Bls[p][(wn * 96 + j * 16 + lrow) * 64
                                              + ((ksi * 4 + quad) ^ rsw) * 8];
            #pragma unroll
            for (int i = 0; i < 4; ++i)
                #pragma unroll
                for (int j = 0; j < 6; ++j)
                    acc[i][j] = __builtin_amdgcn_mfma_f32_16x16x32_bf16(
                        af[i], bf[j], acc[i][j], 0, 0, 0);
        }

        asm volatile("s_waitcnt lgkmcnt(0)" ::: "memory");
        __builtin_amdgcn_sched_barrier(0);
        __builtin_amdgcn_s_barrier();
    }

    #pragma unroll
    for (int i = 0; i < 4; ++i) {
        #pragma unroll
        for (int j = 0; j < 6; ++j) {
            int col = col0 + wn * 96 + j * 16 + lrow;
            bool isphi = col < phi_cols;
            #pragma unroll
            for (int r = 0; r < 4; ++r) {
                int row = row0 + wm * 64 + i * 16 + quad * 4 + r;
                float v = acc[i][j][r];
                if (isphi) v = (v > 0.f) ? (v + 1.f) : __expf(v);  // phi = elu+1
                C[(size_t)row * N + col] = f2bf(v);
            }
        }
    }
}

// ---------------------------------------------------------------------------
// GEMM2: out(fp32) = Y @ w_proj. 128x128 tile, 512 threads (8 waves, 2Mx4N),
// BK=64 dbuf, counted vmcnt(4). Grid 8x32 = 256 blocks, 1 block/CU x 8 waves.
// ---------------------------------------------------------------------------
__global__ __launch_bounds__(512, 1) void gemm_bf16_f32out_k(
    const u16* __restrict__ A, const u16* __restrict__ BT,
    float* __restrict__ C, int N, int K)
{
    __shared__ u16 Als[2][128 * 64];   // 16 KB x2
    __shared__ u16 Bls[2][128 * 64];   // 16 KB x2
    const int tid  = threadIdx.x;
    const int wave = tid >> 6, lane = tid & 63;
    const int quad = lane >> 4, lrow = lane & 15;
    const int wm = wave >> 2, wn = wave & 3;   // 2M x 4N wave grid
    const int row0 = blockIdx.y * 128, col0 = blockIdx.x * 128;
    const int lr = lane >> 3;
    const int lc = ((lane & 7) ^ lr) * 8;
    const int rsw = lrow & 7;
    floatx4 acc[4][2] = {};
    const int NT = K >> 6;

    #pragma unroll
    for (int m = 0; m < 2; ++m) {
        int i = wave * 2 + m;                  // 16 groups of 8 rows
        async_load16(A + (size_t)(row0 + i * 8 + lr) * K + lc, &Als[0][i * 512]);
        async_load16(BT + (size_t)(col0 + i * 8 + lr) * K + lc, &Bls[0][i * 512]);
    }

    for (int t = 0; t < NT; ++t) {
        const int p = t & 1;
        if (t + 1 < NT) {
            const int k0 = (t + 1) << 6;
            #pragma unroll
            for (int m = 0; m < 2; ++m) {
                int i = wave * 2 + m;
                async_load16(A + (size_t)(row0 + i * 8 + lr) * K + k0 + lc,
                             &Als[p ^ 1][i * 512]);
                async_load16(BT + (size_t)(col0 + i * 8 + lr) * K + k0 + lc,
                             &Bls[p ^ 1][i * 512]);
            }
            __builtin_amdgcn_sched_barrier(0);
            asm volatile("s_waitcnt vmcnt(4)" ::: "memory");
        } else {
            asm volatile("s_waitcnt vmcnt(0)" ::: "memory");
        }
        __builtin_amdgcn_s_barrier();
        __builtin_amdgcn_sched_barrier(0);

        #pragma unroll
        for (int ksi = 0; ksi < 2; ++ksi) {
            frag8 af[4], bf[2];
            #pragma unroll
            for (int i = 0; i < 4; ++i)
                af[i] = *(const frag8*)&Als[p][(wm * 64 + i * 16 + lrow) * 64
                                              + ((ksi * 4 + quad) ^ rsw) * 8];
            #pragma unroll
            for (int jn = 0; jn < 2; ++jn)
                bf[jn] = *(const frag8*)&Bls[p][(wn * 32 + jn * 16 + lrow) * 64
                                               + ((ksi * 4 + quad) ^ rsw) * 8];
            #pragma unroll
            for (int i = 0; i < 4; ++i)
                #pragma unroll
                for (int jn = 0; jn < 2; ++jn)
                    acc[i][jn] = __builtin_amdgcn_mfma_f32_16x16x32_bf16(
                        af[i], bf[jn], acc[i][jn], 0, 0, 0);
        }

        asm volatile("s_waitcnt lgkmcnt(0)" ::: "memory");
        __builtin_amdgcn_sched_barrier(0);
        __builtin_amdgcn_s_barrier();
    }

    #pragma unroll
    for (int i = 0; i < 4; ++i)
        #pragma unroll
        for (int jn = 0; jn < 2; ++jn) {
            int col = col0 + wn * 32 + jn * 16 + lrow;
            #pragma unroll
            for (int r = 0; r < 4; ++r) {
                int row = row0 + wm * 64 + i * 16 + quad * 4 + r;
                C[(size_t)row * N + col] = acc[i][jn][r];
            }
        }
}

// ---------------------------------------------------------------------------
// chunk_kv (MFMA): S_c^T = V^T K (bf16 [j][i]); z_c = colsum K; V^T exported
// to VtG (plain stores, no fences) for attn's async staging.
// Grid 1024 blocks ((b*16+h)*32+c), 256 threads = 4 waves.
// ---------------------------------------------------------------------------
__global__ __launch_bounds__(256) void chunk_kv_mfma_k(
    const u16* __restrict__ qkv,
    u16* __restrict__ Spt,
    float* __restrict__ zloc,
    u16* __restrict__ VtG)
{
    __shared__ u16 Kt[64][72];   // K^T [d][s]
    __shared__ u16 Vt[64][72];   // V^T [j][s]
    const int tid  = threadIdx.x;
    const int wave = tid >> 6, lane = tid & 63;
    const int quad = lane >> 4, lrow = lane & 15;
    const int blk = blockIdx.x;
    const int c = blk & 31, h = (blk >> 5) & 15, b = blk >> 9;
    const int t0 = c * 64;
    const u16* base = qkv + (size_t)(b * TB + t0) * 3072 + h * 64;

    #pragma unroll
    for (int m = 0; m < 2; ++m) {
        int chunk = tid + 256 * m;
        int s = chunk >> 3, d0 = (chunk & 7) * 8;
        const u16* row = base + (size_t)s * 3072;
        u16 kv[8], vv[8];
        *(uint4*)kv = *(const uint4*)(row + 1024 + d0);
        *(uint4*)vv = *(const uint4*)(row + 2048 + d0);
        #pragma unroll
        for (int q = 0; q < 8; ++q) { Kt[d0 + q][s] = kv[q]; Vt[d0 + q][s] = vv[q]; }
    }
    __syncthreads();

    // export V^T (row-major [j][s]) for attn's async staging
    #pragma unroll
    for (int m = 0; m < 2; ++m) {
        int e = tid + 256 * m;
        int r = e >> 3, c8 = (e & 7) * 8;
        u16 o[8];
        #pragma unroll
        for (int q = 0; q < 8; ++q) o[q] = Vt[r][c8 + q];
        *(uint4*)(VtG + (size_t)blk * 4096 + r * 64 + c8) = *(uint4*)o;
    }

    frag8 vf[2];
    #pragma unroll
    for (int ks = 0; ks < 2; ++ks)
        vf[ks] = *(const frag8*)&Vt[wave * 16 + lrow][ks * 32 + quad * 8];
    u16* So = Spt + (size_t)blk * 4096;
    #pragma unroll
    for (int jn = 0; jn < 4; ++jn) {
        floatx4 acc = {};
        #pragma unroll
        for (int ks = 0; ks < 2; ++ks) {
            frag8 kf = *(const frag8*)&Kt[jn * 16 + lrow][ks * 32 + quad * 8];
            acc = __builtin_amdgcn_mfma_f32_16x16x32_bf16(vf[ks], kf, acc, 0, 0, 0);
        }
        #pragma unroll
        for (int r = 0; r < 4; ++r) {
            int j = wave * 16 + quad * 4 + r;     // row of S^T
            int i = jn * 16 + lrow;               // col of S^T
            So[j * 64 + i] = f2bf(acc[r]);
        }
    }
    if (tid < 64) {
        float z = 0.f;
        for (int s = 0; s < 64; ++s) z += bf2f(Kt[tid][s]);
        zloc[(size_t)blk * 64 + tid] = z;
    }
}

// ---------------------------------------------------------------------------
// Exclusive prefix over chunk axis, IN-PLACE on bf16 Spt, VECTORIZED:
// each thread owns 4 consecutive bf16 (uint2). Grid: 32 bh x 4 parts = 128.
// ---------------------------------------------------------------------------
__global__ __launch_bounds__(256) void scan_state_k(
    u16* __restrict__ Spt, float* __restrict__ z)
{
    const int bh = blockIdx.x >> 2;
    const int part = blockIdx.x & 3;
    const int e0 = part * 1024 + threadIdx.x * 4;
    const size_t base = (size_t)bh * NCH * 4096;
    float r[4] = {};
    for (int c = 0; c < NCH; ++c) {
        u16* p = Spt + base + (size_t)c * 4096 + e0;
        u16 t[4];
        *(uint2*)t = *(const uint2*)p;
        u16 o[4];
        #pragma unroll
        for (int q = 0; q < 4; ++q) { o[q] = f2bf(r[q]); r[q] += bf2f(t[q]); }
        *(uint2*)p = *(uint2*)o;
    }
    if (part == 0 && threadIdx.x < 64) {
        const size_t zb = (size_t)bh * NCH * 64;
        float rz = 0.f;
        for (int c = 0; c < NCH; ++c) {
            float t = z[zb + c * 64 + threadIdx.x];
            z[zb + c * 64 + threadIdx.x] = rz;
            rz += t;
        }
    }
}

// ---------------------------------------------------------------------------
// attn (MFMA): y = (Q*Sp^T + causal(QK^T)*V) / (q.zp + rowsum + eps), bf16 out.
// All four operand tiles staged ASYNC into unpadded XOR-swizzled LDS
// (Q,K from qkv; Sp from scanned Spt; V^T from VtG). 1024 blocks, 4 waves.
// ---------------------------------------------------------------------------
__global__ __launch_bounds__(256) void attn_mfma_k(
    const u16* __restrict__ qkv,
    const u16* __restrict__ SptG,
    const float* __restrict__ zp,
    const u16* __restrict__ VtG,
    u16* __restrict__ Yb)
{
    __shared__ u16 Qls[64 * 64];   // Q [t][d] swizzled; reused as Y staging (plain)
    __shared__ u16 Kls[64 * 64];   // K [s][d] swizzled
    __shared__ u16 Vls[64 * 64];   // V^T [j][s] swizzled
    __shared__ u16 Sls[64 * 64];   // Sp^T [j][d] swizzled; then masked A [t][s]
    __shared__ float zps[64];
    __shared__ float den4[64][4];
    __shared__ float den[64];

    const int tid  = threadIdx.x;
    const int wave = tid >> 6, lane = tid & 63;
    const int quad = lane >> 4, lrow = lane & 15;
    const int blk = blockIdx.x;
    const int c = blk & 31, h = (blk >> 5) & 15, b = blk >> 9;
    const int t0 = c * 64;
    const int lr = lane >> 3;
    const int lc = ((lane & 7) ^ lr) * 8;
    const int rsw = lrow & 7;
    const u16* qbase = qkv + (size_t)(b * TB + t0) * 3072 + h * 64;

    #pragma unroll
    for (int m = 0; m < 2; ++m) {
        int i = wave * 2 + m;          // 8-row group 0..7
        int r = i * 8 + lr;
        async_load16(qbase + (size_t)r * 3072 + lc,          &Qls[i * 512]);
        async_load16(qbase + (size_t)r * 3072 + 1024 + lc,   &Kls[i * 512]);
        async_load16(SptG + (size_t)blk * 4096 + r * 64 + lc, &Sls[i * 512]);
        async_load16(VtG  + (size_t)blk * 4096 + r * 64 + lc, &Vls[i * 512]);
    }
    if (tid < 64) zps[tid] = zp[(size_t)blk * 64 + tid];
    __syncthreads();

    frag8 qf[2];
    #pragma unroll
    for (int ks = 0; ks < 2; ++ks)
        qf[ks] = *(const frag8*)&Qls[(wave * 16 + lrow) * 64 + ((ks * 4 + quad) ^ rsw) * 8];

    floatx4 yacc[4] = {}, kacc[4] = {};
    #pragma unroll
    for (int jn = 0; jn < 4; ++jn) {
        #pragma unroll
        for (int ks = 0; ks < 2; ++ks) {
            frag8 spf = *(const frag8*)&Sls[(jn * 16 + lrow) * 64 + ((ks * 4 + quad) ^ rsw) * 8];
            yacc[jn] = __builtin_amdgcn_mfma_f32_16x16x32_bf16(qf[ks], spf, yacc[jn], 0, 0, 0);
            frag8 kf = *(const frag8*)&Kls[(jn * 16 + lrow) * 64 + ((ks * 4 + quad) ^ rsw) * 8];
            kacc[jn] = __builtin_amdgcn_mfma_f32_16x16x32_bf16(qf[ks], kf, kacc[jn], 0, 0, 0);
        }
    }
    __syncthreads();   // done reading Sls; reuse for masked A (swizzled [t][s])

    #pragma unroll
    for (int jn = 0; jn < 4; ++jn) {
        int s = jn * 16 + lrow;
        #pragma unroll
        for (int r = 0; r < 4; ++r) {
            int t = wave * 16 + quad * 4 + r;
            float v = (s <= t) ? kacc[jn][r] : 0.f;
            Sls[t * 64 + (((s >> 3) ^ (t & 7)) * 8) + (s & 7)] = f2bf(v);
        }
    }
    __syncthreads();

    // den partials: den[t] = sum_d Q[t][d]*zp[d] + sum_s A[t][s]  (swizzle-aware)
    {
        int t = tid >> 2, seg = tid & 3;
        float p = 0.f;
        #pragma unroll
        for (int g2 = 0; g2 < 2; ++g2) {
            int g = seg * 2 + g2;
            int pq = ((g ^ (t & 7)) * 8);
            const u16* qp = &Qls[t * 64 + pq];
            const u16* ap = &Sls[t * 64 + pq];
            #pragma unroll
            for (int e = 0; e < 8; ++e) {
                p += bf2f(qp[e]) * zps[g * 8 + e] + bf2f(ap[e]);
            }
        }
        den4[t][seg] = p;
    }

    // y += A @ V
    frag8 af2[2];
    #pragma unroll
    for (int ks = 0; ks < 2; ++ks)
        af2[ks] = *(const frag8*)&Sls[(wave * 16 + lrow) * 64 + ((ks * 4 + quad) ^ rsw) * 8];
    #pragma unroll
    for (int jn = 0; jn < 4; ++jn)
        #pragma unroll
        for (int ks = 0; ks < 2; ++ks) {
            frag8 vf = *(const frag8*)&Vls[(jn * 16 + lrow) * 64 + ((ks * 4 + quad) ^ rsw) * 8];
            yacc[jn] = __builtin_amdgcn_mfma_f32_16x16x32_bf16(af2[ks], vf, yacc[jn], 0, 0, 0);
        }
    __syncthreads();
    if (tid < 64) den[tid] = den4[tid][0] + den4[tid][1] + den4[tid][2] + den4[tid][3];
    __syncthreads();

    // epilogue: normalize, stage into Qls (plain layout), vectorized store
    #pragma unroll
    for (int jn = 0; jn < 4; ++jn) {
        #pragma unroll
        for (int r = 0; r < 4; ++r) {
            int t = wave * 16 + quad * 4 + r;
            float inv = 1.f / (den[t] + EPSF);
            Qls[t * 64 + jn * 16 + lrow] = f2bf(yacc[jn][r] * inv);
        }
    }
    __syncthreads();
    {
        int row = tid >> 2, seg = tid & 3;
        size_t o = (size_t)(b * TB + t0 + row) * CCH + h * 64 + seg * 16;
        *(uint4*)(Yb + o)     = *(uint4*)&Qls[row * 64 + seg * 16];
        *(uint4*)(Yb + o + 8) = *(uint4*)&Qls[row * 64 + seg * 16 + 8];
    }
}

// ---------------------------------------------------------------------------
extern "C" void kernel_launch(void* const* d_in, const int* in_sizes, int n_in,
                              void* d_out, int out_size, void* d_ws, size_t ws_size,
                              hipStream_t stream)
{
    const float* x      = (const float*)d_in[0]; // (2,2048,1024) fp32
    const float* w_attn = (const float*)d_in[1]; // (1024,3072)   fp32
    const float* w_proj = (const float*)d_in[2]; // (1024,1024)   fp32
    float* out = (float*)d_out;                  // (2,2048,1024) fp32

    // Workspace layout:
    //   xb    : 4096*1024 bf16  (8 MB)
    //   waT   : 3072*1024 bf16  (6 MB)
    //   wpT   : 1024*1024 bf16  (2 MB)
    //   Yb    : 4096*1024 bf16  (8 MB)
    //   qkv_b : 4096*3072 bf16  (24 MB)
    //   Spt   : 1024*4096 bf16  (8 MB)
    //   VtG   : 1024*4096 bf16  (8 MB)
    //   zloc  : 1024*64   fp32  (0.25 MB)
    u16* xb    = (u16*)d_ws;
    u16* waT   = xb    + (size_t)4096 * 1024;
    u16* wpT   = waT   + (size_t)3072 * 1024;
    u16* Yb    = wpT   + (size_t)1024 * 1024;
    u16* qkv_b = Yb    + (size_t)4096 * 1024;
    u16* Spt   = qkv_b + (size_t)4096 * 3072;
    u16* VtG   = Spt   + (size_t)1024 * 4096;
    float* zloc = (float*)(VtG + (size_t)1024 * 4096);

    // Prep (fused): cvt x, transpose w_attn, transpose w_proj
    prep_k<<<3072, 256, 0, stream>>>(x, w_attn, w_proj, xb, waT, wpT);

    // GEMM1: qkv(bf16) = phi(x @ w_attn) (phi on q,k thirds: cols < 2048)
    // 128x192 tiles, 512 blocks 1D, XCD column-ownership swizzle
    gemm1_k<<<512, 256, 0, stream>>>(xb, waT, qkv_b, 3072, 1024, 2048);

    // Chunked causal linear attention
    chunk_kv_mfma_k<<<1024, 256, 0, stream>>>(qkv_b, Spt, zloc, VtG);
    scan_state_k   <<<128,  256, 0, stream>>>(Spt, zloc);
    attn_mfma_k    <<<1024, 256, 0, stream>>>(qkv_b, Spt, zloc, VtG, Yb);

    // GEMM2: out = Y @ w_proj (128x128 tiles, 512 thr, BK=64 dbuf -> 256 blocks)
    gemm_bf16_f32out_k<<<dim3(8, 32), 512, 0, stream>>>(Yb, wpT, out, 1024, 1024);
}

// Round 11
// 154.007 us; speedup vs baseline: 1.0504x; 1.0267x over previous
//
#include <hip/hip_runtime.h>
#include <hip/hip_bf16.h>
#include <cmath>

// Problem dims (fixed by reference): B=2, T=2048, C=1024, H=16, D=64
// Inputs fp32, output fp32.
#define TB   2048
#define CCH  1024
#define NCH  32      // chunks per (b,h): T / 64
#define EPSF 1e-6f

typedef unsigned short u16;
typedef __attribute__((ext_vector_type(8))) short  frag8;   // 8 bf16 (4 VGPRs)
typedef __attribute__((ext_vector_type(4))) float  floatx4; // MFMA C/D

// RNE float -> bf16 (finite inputs only)
__device__ __forceinline__ u16 f2bf(float f) {
    unsigned int u = __float_as_uint(f);
    unsigned int r = (u + 0x7fffu + ((u >> 16) & 1u)) >> 16;
    return (u16)r;
}
__device__ __forceinline__ float bf2f(u16 v) {
    return __uint_as_float(((unsigned int)v) << 16);
}

// Async global->LDS, 16 B per lane (wave-uniform base + lane*16; unpadded dest).
__device__ __forceinline__ void async_load16(const u16* g, u16* l) {
    __builtin_amdgcn_global_load_lds(
        (const __attribute__((address_space(1))) void*)g,
        (__attribute__((address_space(3))) void*)l,
        16, 0, 0);
}

// ---------------------------------------------------------------------------
// Fused prep: [0,2048) cvt x->bf16 ; [2048,2816) transpose w_attn ; rest w_proj.
// ---------------------------------------------------------------------------
__global__ __launch_bounds__(256) void prep_k(
    const float* __restrict__ x, const float* __restrict__ wa,
    const float* __restrict__ wp,
    u16* __restrict__ xb, u16* __restrict__ waT, u16* __restrict__ wpT)
{
    __shared__ u16 t[64][72];   // t[n][k]
    int blk = blockIdx.x;
    if (blk < 2048) {                       // cvt: 4096*1024 elems, 8/thread
        int i = (blk * 256 + threadIdx.x) * 8;
        float4 a = *(const float4*)(x + i);
        float4 b = *(const float4*)(x + i + 4);
        u16 v[8];
        v[0] = f2bf(a.x); v[1] = f2bf(a.y); v[2] = f2bf(a.z); v[3] = f2bf(a.w);
        v[4] = f2bf(b.x); v[5] = f2bf(b.y); v[6] = f2bf(b.z); v[7] = f2bf(b.w);
        *(uint4*)(xb + i) = *(uint4*)v;
        return;
    }
    const float* in; u16* out; int K, N, bx, by;
    if (blk < 2048 + 768) {                 // w_attn^T: (1024 x 3072) -> (3072 x 1024)
        int tb = blk - 2048; in = wa; out = waT; K = 1024; N = 3072;
        bx = tb % 48; by = tb / 48;
    } else {                                // w_proj^T: (1024 x 1024)
        int tb = blk - 2816; in = wp; out = wpT; K = 1024; N = 1024;
        bx = tb & 15; by = tb >> 4;
    }
    const int k0 = by * 64, n0 = bx * 64;
    #pragma unroll
    for (int i = 0; i < 4; ++i) {
        int rr = (threadIdx.x >> 4) + 16 * i;          // k-row
        int c4 = (threadIdx.x & 15) * 4;               // n-col
        float4 v = *(const float4*)(in + (size_t)(k0 + rr) * N + n0 + c4);
        t[c4 + 0][rr] = f2bf(v.x);
        t[c4 + 1][rr] = f2bf(v.y);
        t[c4 + 2][rr] = f2bf(v.z);
        t[c4 + 3][rr] = f2bf(v.w);
    }
    __syncthreads();
    #pragma unroll
    for (int i = 0; i < 2; ++i) {
        int rr = (threadIdx.x >> 3) + 32 * i;          // n-row
        int c8 = (threadIdx.x & 7) * 8;                // k-chunk
        u16 o[8];
        #pragma unroll
        for (int q = 0; q < 8; ++q) o[q] = t[rr][c8 + q];
        *(uint4*)(out + (size_t)(n0 + rr) * K + k0 + c8) = *(uint4*)o;
    }
}

// ---------------------------------------------------------------------------
// GEMM1: qkv(bf16) = phi(x @ w_attn), phi on cols < phi_cols.
// 128x192 tile, BK=64, dbuf LDS (80 KB -> 2 blocks/CU), counted vmcnt(10),
// full 512-block residency. R4-measured best (session optimum).
// ---------------------------------------------------------------------------
__global__ __launch_bounds__(256, 2) void gemm1_k(
    const u16* __restrict__ A, const u16* __restrict__ BT,
    u16* __restrict__ C, int N, int K, int phi_cols)
{
    __shared__ u16 Als[2][128 * 64];   // 16 KB x2
    __shared__ u16 Bls[2][192 * 64];   // 24 KB x2
    const int tid  = threadIdx.x;
    const int wave = tid >> 6, lane = tid & 63;
    const int quad = lane >> 4, lrow = lane & 15;
    const int wm = wave >> 1, wn = wave & 1;
    const int row0 = blockIdx.y * 128, col0 = blockIdx.x * 192;
    const int lr = lane >> 3;
    const int lc = ((lane & 7) ^ lr) * 8;
    const int rsw = lrow & 7;
    floatx4 acc[4][6] = {};
    const int NT = K >> 6;                 // 16 K-tiles

    #pragma unroll
    for (int m = 0; m < 4; ++m) {
        int i = wave * 4 + m;
        async_load16(A + (size_t)(row0 + i * 8 + lr) * K + lc, &Als[0][i * 512]);
    }
    #pragma unroll
    for (int m = 0; m < 6; ++m) {
        int i = wave * 6 + m;
        async_load16(BT + (size_t)(col0 + i * 8 + lr) * K + lc, &Bls[0][i * 512]);
    }

    for (int t = 0; t < NT; ++t) {
        const int p = t & 1;
        if (t + 1 < NT) {
            const int k0 = (t + 1) << 6;
            #pragma unroll
            for (int m = 0; m < 4; ++m) {
                int i = wave * 4 + m;
                async_load16(A + (size_t)(row0 + i * 8 + lr) * K + k0 + lc,
                             &Als[p ^ 1][i * 512]);
            }
            #pragma unroll
            for (int m = 0; m < 6; ++m) {
                int i = wave * 6 + m;
                async_load16(BT + (size_t)(col0 + i * 8 + lr) * K + k0 + lc,
                             &Bls[p ^ 1][i * 512]);
            }
            __builtin_amdgcn_sched_barrier(0);
            asm volatile("s_waitcnt vmcnt(10)" ::: "memory");   // tile t landed
        } else {
            asm volatile("s_waitcnt vmcnt(0)" ::: "memory");
        }
        __builtin_amdgcn_s_barrier();      // all waves' tile-t loads visible
        __builtin_amdgcn_sched_barrier(0);

        #pragma unroll
        for (int ksi = 0; ksi < 2; ++ksi) {
            frag8 af[4], bf[6];
            #pragma unroll
            for (int i = 0; i < 4; ++i)
                af[i] = *(const frag8*)&Als[p][(wm * 64 + i * 16 + lrow) * 64
                                              + ((ksi * 4 + quad) ^ rsw) * 8];
            #pragma unroll
            for (int j = 0; j < 6; ++j)
                bf[j] = *(const frag8*)&Bls[p][(wn * 96 + j * 16 + lrow) * 64
                                              + ((ksi * 4 + quad) ^ rsw) * 8];
            #pragma unroll
            for (int i = 0; i < 4; ++i)
                #pragma unroll
                for (int j = 0; j < 6; ++j)
                    acc[i][j] = __builtin_amdgcn_mfma_f32_16x16x32_bf16(
                        af[i], bf[j], acc[i][j], 0, 0, 0);
        }

        // drain this wave's ds_reads before next iter overwrites buf p
        asm volatile("s_waitcnt lgkmcnt(0)" ::: "memory");
        __builtin_amdgcn_sched_barrier(0);
        __builtin_amdgcn_s_barrier();
    }

    #pragma unroll
    for (int i = 0; i < 4; ++i) {
        #pragma unroll
        for (int j = 0; j < 6; ++j) {
            int col = col0 + wn * 96 + j * 16 + lrow;
            bool isphi = col < phi_cols;
            #pragma unroll
            for (int r = 0; r < 4; ++r) {
                int row = row0 + wm * 64 + i * 16 + quad * 4 + r;
                float v = acc[i][j][r];
                if (isphi) v = (v > 0.f) ? (v + 1.f) : __expf(v);  // phi = elu+1
                C[(size_t)row * N + col] = f2bf(v);
            }
        }
    }
}

// ---------------------------------------------------------------------------
// GEMM2: out(fp32) = Y @ w_proj. 128x64 tile, BK=64, dbuf, vmcnt(6). R4 form.
// ---------------------------------------------------------------------------
__global__ __launch_bounds__(256, 2) void gemm_bf16_f32out_k(
    const u16* __restrict__ A, const u16* __restrict__ BT,
    float* __restrict__ C, int N, int K)
{
    __shared__ u16 Als[2][128 * 64];
    __shared__ u16 Bls[2][64 * 64];
    const int tid  = threadIdx.x;
    const int wave = tid >> 6, lane = tid & 63;
    const int quad = lane >> 4, lrow = lane & 15;
    const int wm = wave >> 1, wn = wave & 1;
    const int row0 = blockIdx.y * 128, col0 = blockIdx.x * 64;
    const int lr = lane >> 3;
    const int lc = ((lane & 7) ^ lr) * 8;
    const int rsw = lrow & 7;
    floatx4 acc[4][2] = {};
    const int NT = K >> 6;

    #pragma unroll
    for (int m = 0; m < 4; ++m) {
        int i = wave * 4 + m;
        async_load16(A + (size_t)(row0 + i * 8 + lr) * K + lc, &Als[0][i * 512]);
    }
    #pragma unroll
    for (int m = 0; m < 2; ++m) {
        int i = wave * 2 + m;
        async_load16(BT + (size_t)(col0 + i * 8 + lr) * K + lc, &Bls[0][i * 512]);
    }

    for (int t = 0; t < NT; ++t) {
        const int p = t & 1;
        if (t + 1 < NT) {
            const int k0 = (t + 1) << 6;
            #pragma unroll
            for (int m = 0; m < 4; ++m) {
                int i = wave * 4 + m;
                async_load16(A + (size_t)(row0 + i * 8 + lr) * K + k0 + lc,
                             &Als[p ^ 1][i * 512]);
            }
            #pragma unroll
            for (int m = 0; m < 2; ++m) {
                int i = wave * 2 + m;
                async_load16(BT + (size_t)(col0 + i * 8 + lr) * K + k0 + lc,
                             &Bls[p ^ 1][i * 512]);
            }
            __builtin_amdgcn_sched_barrier(0);
            asm volatile("s_waitcnt vmcnt(6)" ::: "memory");
        } else {
            asm volatile("s_waitcnt vmcnt(0)" ::: "memory");
        }
        __builtin_amdgcn_s_barrier();
        __builtin_amdgcn_sched_barrier(0);

        #pragma unroll
        for (int ksi = 0; ksi < 2; ++ksi) {
            frag8 af[4], bf[2];
            #pragma unroll
            for (int i = 0; i < 4; ++i)
                af[i] = *(const frag8*)&Als[p][(wm * 64 + i * 16 + lrow) * 64
                                              + ((ksi * 4 + quad) ^ rsw) * 8];
            #pragma unroll
            for (int jn = 0; jn < 2; ++jn)
                bf[jn] = *(const frag8*)&Bls[p][(wn * 32 + jn * 16 + lrow) * 64
                                               + ((ksi * 4 + quad) ^ rsw) * 8];
            #pragma unroll
            for (int i = 0; i < 4; ++i)
                #pragma unroll
                for (int jn = 0; jn < 2; ++jn)
                    acc[i][jn] = __builtin_amdgcn_mfma_f32_16x16x32_bf16(
                        af[i], bf[jn], acc[i][jn], 0, 0, 0);
        }

        asm volatile("s_waitcnt lgkmcnt(0)" ::: "memory");
        __builtin_amdgcn_sched_barrier(0);
        __builtin_amdgcn_s_barrier();
    }

    #pragma unroll
    for (int i = 0; i < 4; ++i)
        #pragma unroll
        for (int jn = 0; jn < 2; ++jn) {
            int col = col0 + wn * 32 + jn * 16 + lrow;
            #pragma unroll
            for (int r = 0; r < 4; ++r) {
                int row = row0 + wm * 64 + i * 16 + quad * 4 + r;
                C[(size_t)row * N + col] = acc[i][jn][r];
            }
        }
}

// ---------------------------------------------------------------------------
// chunk_kv (MFMA): S_c^T = V^T K (bf16 [j][i]); z_c = colsum K; V^T exported
// to VtG (plain stores, no fences) for attn's async staging.
// Grid 1024 blocks ((b*16+h)*32+c), 256 threads = 4 waves.
// ---------------------------------------------------------------------------
__global__ __launch_bounds__(256) void chunk_kv_mfma_k(
    const u16* __restrict__ qkv,
    u16* __restrict__ Spt,
    float* __restrict__ zloc,
    u16* __restrict__ VtG)
{
    __shared__ u16 Kt[64][72];   // K^T [d][s]
    __shared__ u16 Vt[64][72];   // V^T [j][s]
    const int tid  = threadIdx.x;
    const int wave = tid >> 6, lane = tid & 63;
    const int quad = lane >> 4, lrow = lane & 15;
    const int blk = blockIdx.x;
    const int c = blk & 31, h = (blk >> 5) & 15, b = blk >> 9;
    const int t0 = c * 64;
    const u16* base = qkv + (size_t)(b * TB + t0) * 3072 + h * 64;

    #pragma unroll
    for (int m = 0; m < 2; ++m) {
        int chunk = tid + 256 * m;
        int s = chunk >> 3, d0 = (chunk & 7) * 8;
        const u16* row = base + (size_t)s * 3072;
        u16 kv[8], vv[8];
        *(uint4*)kv = *(const uint4*)(row + 1024 + d0);
        *(uint4*)vv = *(const uint4*)(row + 2048 + d0);
        #pragma unroll
        for (int q = 0; q < 8; ++q) { Kt[d0 + q][s] = kv[q]; Vt[d0 + q][s] = vv[q]; }
    }
    __syncthreads();

    // export V^T (row-major [j][s]) for attn's async staging
    #pragma unroll
    for (int m = 0; m < 2; ++m) {
        int e = tid + 256 * m;
        int r = e >> 3, c8 = (e & 7) * 8;
        u16 o[8];
        #pragma unroll
        for (int q = 0; q < 8; ++q) o[q] = Vt[r][c8 + q];
        *(uint4*)(VtG + (size_t)blk * 4096 + r * 64 + c8) = *(uint4*)o;
    }

    frag8 vf[2];
    #pragma unroll
    for (int ks = 0; ks < 2; ++ks)
        vf[ks] = *(const frag8*)&Vt[wave * 16 + lrow][ks * 32 + quad * 8];
    u16* So = Spt + (size_t)blk * 4096;
    #pragma unroll
    for (int jn = 0; jn < 4; ++jn) {
        floatx4 acc = {};
        #pragma unroll
        for (int ks = 0; ks < 2; ++ks) {
            frag8 kf = *(const frag8*)&Kt[jn * 16 + lrow][ks * 32 + quad * 8];
            acc = __builtin_amdgcn_mfma_f32_16x16x32_bf16(vf[ks], kf, acc, 0, 0, 0);
        }
        #pragma unroll
        for (int r = 0; r < 4; ++r) {
            int j = wave * 16 + quad * 4 + r;     // row of S^T
            int i = jn * 16 + lrow;               // col of S^T
            So[j * 64 + i] = f2bf(acc[r]);
        }
    }
    if (tid < 64) {
        float z = 0.f;
        for (int s = 0; s < 64; ++s) z += bf2f(Kt[tid][s]);
        zloc[(size_t)blk * 64 + tid] = z;
    }
}

// ---------------------------------------------------------------------------
// Exclusive prefix over chunk axis, IN-PLACE on bf16 Spt, VECTORIZED:
// each thread owns 4 consecutive bf16 (uint2). Grid: 32 bh x 4 parts = 128.
// ---------------------------------------------------------------------------
__global__ __launch_bounds__(256) void scan_state_k(
    u16* __restrict__ Spt, float* __restrict__ z)
{
    const int bh = blockIdx.x >> 2;
    const int part = blockIdx.x & 3;
    const int e0 = part * 1024 + threadIdx.x * 4;
    const size_t base = (size_t)bh * NCH * 4096;
    float r[4] = {};
    for (int c = 0; c < NCH; ++c) {
        u16* p = Spt + base + (size_t)c * 4096 + e0;
        u16 t[4];
        *(uint2*)t = *(const uint2*)p;
        u16 o[4];
        #pragma unroll
        for (int q = 0; q < 4; ++q) { o[q] = f2bf(r[q]); r[q] += bf2f(t[q]); }
        *(uint2*)p = *(uint2*)o;
    }
    if (part == 0 && threadIdx.x < 64) {
        const size_t zb = (size_t)bh * NCH * 64;
        float rz = 0.f;
        for (int c = 0; c < NCH; ++c) {
            float t = z[zb + c * 64 + threadIdx.x];
            z[zb + c * 64 + threadIdx.x] = rz;
            rz += t;
        }
    }
}

// ---------------------------------------------------------------------------
// attn (MFMA): y = (Q*Sp^T + causal(QK^T)*V) / (q.zp + rowsum + eps), bf16 out.
// All four operand tiles staged ASYNC into unpadded XOR-swizzled LDS
// (Q,K from qkv; Sp from scanned Spt; V^T from VtG). 1024 blocks, 4 waves.
// ---------------------------------------------------------------------------
__global__ __launch_bounds__(256) void attn_mfma_k(
    const u16* __restrict__ qkv,
    const u16* __restrict__ SptG,
    const float* __restrict__ zp,
    const u16* __restrict__ VtG,
    u16* __restrict__ Yb)
{
    __shared__ u16 Qls[64 * 64];   // Q [t][d] swizzled; reused as Y staging (plain)
    __shared__ u16 Kls[64 * 64];   // K [s][d] swizzled
    __shared__ u16 Vls[64 * 64];   // V^T [j][s] swizzled
    __shared__ u16 Sls[64 * 64];   // Sp^T [j][d] swizzled; then masked A [t][s]
    __shared__ float zps[64];
    __shared__ float den4[64][4];
    __shared__ float den[64];

    const int tid  = threadIdx.x;
    const int wave = tid >> 6, lane = tid & 63;
    const int quad = lane >> 4, lrow = lane & 15;
    const int blk = blockIdx.x;
    const int c = blk & 31, h = (blk >> 5) & 15, b = blk >> 9;
    const int t0 = c * 64;
    const int lr = lane >> 3;
    const int lc = ((lane & 7) ^ lr) * 8;
    const int rsw = lrow & 7;
    const u16* qbase = qkv + (size_t)(b * TB + t0) * 3072 + h * 64;

    #pragma unroll
    for (int m = 0; m < 2; ++m) {
        int i = wave * 2 + m;          // 8-row group 0..7
        int r = i * 8 + lr;
        async_load16(qbase + (size_t)r * 3072 + lc,          &Qls[i * 512]);
        async_load16(qbase + (size_t)r * 3072 + 1024 + lc,   &Kls[i * 512]);
        async_load16(SptG + (size_t)blk * 4096 + r * 64 + lc, &Sls[i * 512]);
        async_load16(VtG  + (size_t)blk * 4096 + r * 64 + lc, &Vls[i * 512]);
    }
    if (tid < 64) zps[tid] = zp[(size_t)blk * 64 + tid];
    __syncthreads();

    frag8 qf[2];
    #pragma unroll
    for (int ks = 0; ks < 2; ++ks)
        qf[ks] = *(const frag8*)&Qls[(wave * 16 + lrow) * 64 + ((ks * 4 + quad) ^ rsw) * 8];

    floatx4 yacc[4] = {}, kacc[4] = {};
    #pragma unroll
    for (int jn = 0; jn < 4; ++jn) {
        #pragma unroll
        for (int ks = 0; ks < 2; ++ks) {
            frag8 spf = *(const frag8*)&Sls[(jn * 16 + lrow) * 64 + ((ks * 4 + quad) ^ rsw) * 8];
            yacc[jn] = __builtin_amdgcn_mfma_f32_16x16x32_bf16(qf[ks], spf, yacc[jn], 0, 0, 0);
            frag8 kf = *(const frag8*)&Kls[(jn * 16 + lrow) * 64 + ((ks * 4 + quad) ^ rsw) * 8];
            kacc[jn] = __builtin_amdgcn_mfma_f32_16x16x32_bf16(qf[ks], kf, kacc[jn], 0, 0, 0);
        }
    }
    __syncthreads();   // done reading Sls; reuse for masked A (swizzled [t][s])

    #pragma unroll
    for (int jn = 0; jn < 4; ++jn) {
        int s = jn * 16 + lrow;
        #pragma unroll
        for (int r = 0; r < 4; ++r) {
            int t = wave * 16 + quad * 4 + r;
            float v = (s <= t) ? kacc[jn][r] : 0.f;
            Sls[t * 64 + (((s >> 3) ^ (t & 7)) * 8) + (s & 7)] = f2bf(v);
        }
    }
    __syncthreads();

    // den partials: den[t] = sum_d Q[t][d]*zp[d] + sum_s A[t][s]  (swizzle-aware)
    {
        int t = tid >> 2, seg = tid & 3;
        float p = 0.f;
        #pragma unroll
        for (int g2 = 0; g2 < 2; ++g2) {
            int g = seg * 2 + g2;
            int pq = ((g ^ (t & 7)) * 8);
            const u16* qp = &Qls[t * 64 + pq];
            const u16* ap = &Sls[t * 64 + pq];
            #pragma unroll
            for (int e = 0; e < 8; ++e) {
                p += bf2f(qp[e]) * zps[g * 8 + e] + bf2f(ap[e]);
            }
        }
        den4[t][seg] = p;
    }

    // y += A @ V
    frag8 af2[2];
    #pragma unroll
    for (int ks = 0; ks < 2; ++ks)
        af2[ks] = *(const frag8*)&Sls[(wave * 16 + lrow) * 64 + ((ks * 4 + quad) ^ rsw) * 8];
    #pragma unroll
    for (int jn = 0; jn < 4; ++jn)
        #pragma unroll
        for (int ks = 0; ks < 2; ++ks) {
            frag8 vf = *(const frag8*)&Vls[(jn * 16 + lrow) * 64 + ((ks * 4 + quad) ^ rsw) * 8];
            yacc[jn] = __builtin_amdgcn_mfma_f32_16x16x32_bf16(af2[ks], vf, yacc[jn], 0, 0, 0);
        }
    __syncthreads();
    if (tid < 64) den[tid] = den4[tid][0] + den4[tid][1] + den4[tid][2] + den4[tid][3];
    __syncthreads();

    // epilogue: normalize, stage into Qls (plain layout), vectorized store
    #pragma unroll
    for (int jn = 0; jn < 4; ++jn) {
        #pragma unroll
        for (int r = 0; r < 4; ++r) {
            int t = wave * 16 + quad * 4 + r;
            float inv = 1.f / (den[t] + EPSF);
            Qls[t * 64 + jn * 16 + lrow] = f2bf(yacc[jn][r] * inv);
        }
    }
    __syncthreads();
    {
        int row = tid >> 2, seg = tid & 3;
        size_t o = (size_t)(b * TB + t0 + row) * CCH + h * 64 + seg * 16;
        *(uint4*)(Yb + o)     = *(uint4*)&Qls[row * 64 + seg * 16];
        *(uint4*)(Yb + o + 8) = *(uint4*)&Qls[row * 64 + seg * 16 + 8];
    }
}

// ---------------------------------------------------------------------------
extern "C" void kernel_launch(void* const* d_in, const int* in_sizes, int n_in,
                              void* d_out, int out_size, void* d_ws, size_t ws_size,
                              hipStream_t stream)
{
    const float* x      = (const float*)d_in[0]; // (2,2048,1024) fp32
    const float* w_attn = (const float*)d_in[1]; // (1024,3072)   fp32
    const float* w_proj = (const float*)d_in[2]; // (1024,1024)   fp32
    float* out = (float*)d_out;                  // (2,2048,1024) fp32

    // Workspace layout:
    //   xb    : 4096*1024 bf16  (8 MB)
    //   waT   : 3072*1024 bf16  (6 MB)
    //   wpT   : 1024*1024 bf16  (2 MB)
    //   Yb    : 4096*1024 bf16  (8 MB)
    //   qkv_b : 4096*3072 bf16  (24 MB)
    //   Spt   : 1024*4096 bf16  (8 MB)
    //   VtG   : 1024*4096 bf16  (8 MB)
    //   zloc  : 1024*64   fp32  (0.25 MB)
    u16* xb    = (u16*)d_ws;
    u16* waT   = xb    + (size_t)4096 * 1024;
    u16* wpT   = waT   + (size_t)3072 * 1024;
    u16* Yb    = wpT   + (size_t)1024 * 1024;
    u16* qkv_b = Yb    + (size_t)4096 * 1024;
    u16* Spt   = qkv_b + (size_t)4096 * 3072;
    u16* VtG   = Spt   + (size_t)1024 * 4096;
    float* zloc = (float*)(VtG + (size_t)1024 * 4096);

    // Prep (fused): cvt x, transpose w_attn, transpose w_proj
    prep_k<<<3072, 256, 0, stream>>>(x, w_attn, w_proj, xb, waT, wpT);

    // GEMM1: qkv(bf16) = phi(x @ w_attn) (phi on q,k thirds: cols < 2048)
    gemm1_k<<<dim3(16, 32), 256, 0, stream>>>(xb, waT, qkv_b, 3072, 1024, 2048);

    // Chunked causal linear attention
    chunk_kv_mfma_k<<<1024, 256, 0, stream>>>(qkv_b, Spt, zloc, VtG);
    scan_state_k   <<<128,  256, 0, stream>>>(Spt, zloc);
    attn_mfma_k    <<<1024, 256, 0, stream>>>(qkv_b, Spt, zloc, VtG, Yb);

    // GEMM2: out = Y @ w_proj
    gemm_bf16_f32out_k<<<dim3(16, 32), 256, 0, stream>>>(Yb, wpT, out, 1024, 1024);
}